// Round 4
// baseline (1344.241 us; speedup 1.0000x reference)
//
#include <hip/hip_runtime.h>
#include <stdint.h>

#define NN 32768            // nodes
#define HID 512
#define EM 131072           // mol edges
#define EP 196608           // pro edges

typedef _Float16 h8 __attribute__((ext_vector_type(8)));
typedef _Float16 h2 __attribute__((ext_vector_type(2)));
typedef float f4 __attribute__((ext_vector_type(4)));

// ---------------- fused weight conversion: 12 transpose+cast jobs in one launch ----------------
struct ConvJobs {
    const float* src[12];
    _Float16* dst[12];
    int K[12], N[12], Kp[12];
    int blk0[13];   // cumulative block starts
};

__global__ void conv_all(ConvJobs j) {
    int blk = blockIdx.x, job = 0;
    while (blk >= j.blk0[job + 1]) ++job;
    int idx = (blk - j.blk0[job]) * 256 + threadIdx.x;
    int Kp = j.Kp[job], N = j.N[job], K = j.K[job];
    if (idx >= N * Kp) return;
    int n = idx / Kp, k = idx - n * Kp;
    j.dst[job][idx] = (k < K) ? (_Float16)j.src[job][(size_t)k * N + n] : (_Float16)0.f;
}

// pad+cast features fp32 [NN,F] -> fp16 [NN,128]; z selects branch (combined mode)
__global__ void pad_x2(const float* s0, const float* s1, int F0, int F1, _Float16* dstb) {
    int z = blockIdx.z;
    const float* src = z ? s1 : s0;
    int F = z ? F1 : F0;
    _Float16* dst = dstb + (size_t)z * NN * 128;
    int idx = blockIdx.x * 256 + threadIdx.x;
    int i = idx >> 7, jj = idx & 127;
    dst[idx] = (jj < F) ? (_Float16)src[(size_t)i * F + jj] : (_Float16)0.f;
}

// ---------------- CSR build (both branches always, meta arrays are [2][...]) ----------------
__global__ void init_deg(int* deg) {
    deg[(size_t)blockIdx.z * NN + blockIdx.x * 256 + threadIdx.x] = 1;  // self loop
}

__global__ void count_edges2(const int* c0, int E0, const int* c1, int E1, int* deg) {
    int i = blockIdx.x * 256 + threadIdx.x;
    if (i < E0) atomicAdd(&deg[c0[i]], 1);
    else { i -= E0; if (i < E1) atomicAdd(&deg[NN + c1[i]], 1); }
}

__global__ void compute_dis(const int* deg, float* dis) {
    int i = blockIdx.z * NN + blockIdx.x * 256 + threadIdx.x;
    dis[i] = rsqrtf((float)deg[i]);
}

// exclusive scan of (deg-1); one block per branch (blockIdx.z)
__global__ void scan_offsets(const int* degb, int* offsb, int* curb) {
    const int* deg = degb + blockIdx.z * NN;
    int* offs = offsb + blockIdx.z * (NN + 1);
    int* cur = curb + blockIdx.z * NN;
    __shared__ int part[1024];
    int t = threadIdx.x, base = t * 32;
    int loc[32], sum = 0;
    for (int j = 0; j < 32; ++j) { loc[j] = sum; sum += deg[base + j] - 1; }
    part[t] = sum;
    __syncthreads();
    for (int o = 1; o < 1024; o <<= 1) {
        int v = (t >= o) ? part[t - o] : 0;
        __syncthreads();
        part[t] += v;
        __syncthreads();
    }
    int pre = (t == 0) ? 0 : part[t - 1];
    for (int j = 0; j < 32; ++j) { int x = pre + loc[j]; offs[base + j] = x; cur[base + j] = x; }
    if (t == 1023) offs[NN] = part[1023];
}

__global__ void scatter2(const int* r0, const int* c0, int E0,
                         const int* r1, const int* c1, int E1,
                         int* cur, int* s0, int* s1) {
    int i = blockIdx.x * 256 + threadIdx.x;
    if (i < E0) { int p = atomicAdd(&cur[c0[i]], 1); s0[p] = r0[i]; }
    else { i -= E0; if (i < E1) { int p = atomicAdd(&cur[NN + c1[i]], 1); s1[p] = r1[i]; } }
}

// ---------------- aggregation: sup = 0.8*(D^-1/2 (A+I) D^-1/2 prev) + 0.2*h0 ----------------
__global__ void agg_kernel(const _Float16* prevb, const _Float16* h0b, const float* disb,
                           const int* offsb, const int* sr0, const int* sr1,
                           _Float16* supb, int mzadd) {
    const int z = blockIdx.z, mz = z + mzadd;
    const _Float16* prev = prevb + (size_t)z * NN * HID;
    const _Float16* h0 = h0b + (size_t)z * NN * HID;
    _Float16* sup = supb + (size_t)z * NN * HID;
    const float* dis = disb + mz * NN;
    const int* offs = offsb + mz * (NN + 1);
    const int* srow = mz ? sr1 : sr0;
    const int i = blockIdx.x, t = threadIdx.x;
    const size_t base = (size_t)i * HID + t * 2;
    const int e0 = offs[i], e1 = offs[i + 1];
    float a0 = 0.f, a1 = 0.f;
    int e = e0;
    for (; e + 1 < e1; e += 2) {  // unroll-2: two independent gathers in flight
        int ra = srow[e], rb = srow[e + 1];
        float sa = dis[ra], sb = dis[rb];
        h2 va = *(const h2*)&prev[(size_t)ra * HID + t * 2];
        h2 vb = *(const h2*)&prev[(size_t)rb * HID + t * 2];
        a0 += sa * (float)va[0] + sb * (float)vb[0];
        a1 += sa * (float)va[1] + sb * (float)vb[1];
    }
    if (e < e1) {
        int ra = srow[e];
        float sa = dis[ra];
        h2 va = *(const h2*)&prev[(size_t)ra * HID + t * 2];
        a0 += sa * (float)va[0];
        a1 += sa * (float)va[1];
    }
    float si = dis[i];
    h2 pv = *(const h2*)&prev[base];
    h2 hv = *(const h2*)&h0[base];
    float r0 = 0.8f * si * (a0 + si * (float)pv[0]) + 0.2f * (float)hv[0];
    float r1 = 0.8f * si * (a1 + si * (float)pv[1]) + 0.2f * (float)hv[1];
    h2 o; o[0] = (_Float16)r0; o[1] = (_Float16)r1;
    *(h2*)&sup[base] = o;
}

// ---------------- MFMA GEMM: barrier-free, direct-to-register fragments ----------------
// 128x128 tile, 4 waves 2x2, 4x4 16x16x32 f16 frags/wave. No LDS: A and B frags are
// 16B/lane global loads (wave touches 16 rows x 4 consecutive 16B = 16 full 64B lines).
// Compiler interleaves loads with MFMA under fine-grained vmcnt (AITER-style K-loop).
enum { EPI_RELU2 = 0, EPI_BIAS = 1, EPI_GCN = 2 };

struct GArgs {
    const _Float16* A[2];
    const _Float16* BT[2];
    const float* bias[2];
    _Float16* C[2];
    _Float16* C2[2];
    const _Float16* S[2];
    _Float16* P[2];
    int coff[2];
};

template <int EPI, int K>
__global__ __launch_bounds__(256) void gemm_k(GArgs g, int ldc) {
    const int z = blockIdx.z;
    const _Float16* __restrict__ A = g.A[z];
    const _Float16* __restrict__ BT = g.BT[z];
    const int tid = threadIdx.x;
    const int wave = tid >> 6, lane = tid & 63;
    const int row0 = blockIdx.x * 128, col0 = blockIdx.y * 128;
    const int wm = wave & 1, wn = wave >> 1;
    const int l15 = lane & 15, lq = lane >> 4;
    f4 acc[4][4] = {};
    // A frag layout: A[m = l15][k = lq*8 + j]  (16x16x32 f16 A-operand mapping)
    const _Float16* Ab = A + (size_t)(row0 + wm * 64 + l15) * K + lq * 8;
    const _Float16* Bb = BT + (size_t)(col0 + wn * 64 + l15) * K + lq * 8;
    #pragma unroll
    for (int ph = 0; ph < (K >> 5); ++ph) {   // 32 elements of K per phase
        h8 af[4], bf[4];
        #pragma unroll
        for (int t = 0; t < 4; ++t) {
            af[t] = *(const h8*)(Ab + (size_t)t * 16 * K + ph * 32);
            bf[t] = *(const h8*)(Bb + (size_t)t * 16 * K + ph * 32);
        }
        #pragma unroll
        for (int rt = 0; rt < 4; ++rt)
            #pragma unroll
            for (int ct = 0; ct < 4; ++ct)
                acc[rt][ct] = __builtin_amdgcn_mfma_f32_16x16x32_f16(af[rt], bf[ct], acc[rt][ct], 0, 0, 0);
    }
    // C/D frag mapping: col=lane&15, row=(lane>>4)*4+r (m89-verified)
    #pragma unroll
    for (int rt = 0; rt < 4; ++rt) {
        #pragma unroll
        for (int ct = 0; ct < 4; ++ct) {
            const int col = col0 + wn * 64 + ct * 16 + l15;
            #pragma unroll
            for (int r = 0; r < 4; ++r) {
                const int row = row0 + wm * 64 + rt * 16 + lq * 4 + r;
                float v = acc[rt][ct][r];
                if (EPI == EPI_RELU2) {
                    v = fmaxf(v + g.bias[z][col], 0.f);
                    g.C[z][(size_t)row * ldc + col] = (_Float16)v;
                    if (g.C2[z]) g.C2[z][(size_t)row * ldc + col] = (_Float16)v;
                } else if (EPI == EPI_BIAS) {
                    g.C[z][(size_t)row * ldc + g.coff[z] + col] = (_Float16)(v + g.bias[z][col]);
                } else {  // EPI_GCN: prev = relu(support + support@W) + prev
                    const size_t idx = (size_t)row * HID + col;
                    float nv = fmaxf((float)g.S[z][idx] + v, 0.f) + (float)g.P[z][idx];
                    g.P[z][idx] = (_Float16)nv;
                }
            }
        }
    }
}

// ---------------- final projection: out[i] = x2[i,:512] . w_o + b_o ----------------
__global__ void final_dot(const _Float16* __restrict__ x2, const float* __restrict__ w,
                          const float* __restrict__ b, float* __restrict__ out) {
    int wave = threadIdx.x >> 6, lane = threadIdx.x & 63;
    int row = blockIdx.x * 4 + wave;
    h8 v = *(const h8*)&x2[(size_t)row * 512 + lane * 8];
    float s = 0.f;
    #pragma unroll
    for (int j = 0; j < 8; ++j) s += (float)v[j] * w[lane * 8 + j];
    #pragma unroll
    for (int off = 32; off > 0; off >>= 1) s += __shfl_down(s, off);
    if (lane == 0) out[row] = s + b[0];
}

// ---------------- workspace plan ----------------
struct WS {
    int *deg, *offs, *cur, *srow0, *srow1;
    float* dis;
    _Float16 *winT, *wsT, *woutT, *fc1T, *fc2T;
    _Float16 *xpad, *h0, *prev, *sup, *xc;
    size_t total;
};

static WS plan(char* base, bool comb) {
    size_t off = 0;
    auto al = [&](size_t n) { off = (off + 255) & ~(size_t)255; size_t o = off; off += n; return base + o; };
    WS w;
    w.deg   = (int*)al(2 * NN * 4);
    w.dis   = (float*)al(2 * NN * 4);
    w.offs  = (int*)al(2 * (NN + 1) * 4);
    w.cur   = (int*)al(2 * NN * 4);
    w.srow0 = (int*)al((size_t)EM * 4);
    w.srow1 = (int*)al((size_t)EP * 4);
    w.winT  = (_Float16*)al(2 * 512 * 128 * 2);
    w.wsT   = (_Float16*)al((size_t)2 * 3 * 512 * 512 * 2);
    w.woutT = (_Float16*)al(2 * 128 * 512 * 2);
    w.fc1T  = (_Float16*)al(1024 * 256 * 2);
    w.fc2T  = (_Float16*)al((size_t)512 * 1024 * 2);
    size_t nb = comb ? 2 : 1;
    w.xpad = (_Float16*)al(nb * NN * 128 * 2);
    w.h0   = (_Float16*)al(nb * NN * HID * 2);   // h0 and prev contiguous: x1 [NN,1024] aliases h0(+prev)
    w.prev = (_Float16*)al(nb * NN * HID * 2);
    w.sup  = (_Float16*)al(nb * NN * HID * 2);
    w.xc   = (_Float16*)al((size_t)NN * 256 * 2);
    w.total = off;
    return w;
}

// ---------------- host orchestration ----------------
extern "C" void kernel_launch(void* const* d_in, const int* in_sizes, int n_in,
                              void* d_out, int out_size, void* d_ws, size_t ws_size,
                              hipStream_t stream) {
    const float* mol_x   = (const float*)d_in[0];
    const int*   mol_ei  = (const int*)d_in[1];
    const float* pro_x   = (const float*)d_in[2];
    const int*   pro_ei  = (const int*)d_in[3];
    const float* win[2]  = {(const float*)d_in[4], (const float*)d_in[9]};
    const float* bin[2]  = {(const float*)d_in[5], (const float*)d_in[10]};
    const float* ws3[2]  = {(const float*)d_in[6], (const float*)d_in[11]};
    const float* wo[2]   = {(const float*)d_in[7], (const float*)d_in[12]};
    const float* bo[2]   = {(const float*)d_in[8], (const float*)d_in[13]};
    const float* w_fc1   = (const float*)d_in[14];
    const float* b_fc1   = (const float*)d_in[15];
    const float* w_fc2   = (const float*)d_in[16];
    const float* b_fc2   = (const float*)d_in[17];
    const float* w_o     = (const float*)d_in[18];
    const float* b_o     = (const float*)d_in[19];
    const int F[2] = {78, 54};

    char* wsb = (char*)d_ws;
    WS w = plan(wsb, true);
    const bool comb = (w.total <= ws_size);
    if (!comb) w = plan(wsb, false);
    const size_t BSTR = comb ? (size_t)NN * HID : 0;       // branch stride for big fp16 arrays
    const size_t XSTR = comb ? (size_t)NN * 128 : 0;

    // --- 1. all weight conversions in one launch ---
    ConvJobs j;
    int nblk = 0, ji = 0;
    auto addjob = [&](const float* s, _Float16* d, int K, int N, int Kp) {
        j.src[ji] = s; j.dst[ji] = d; j.K[ji] = K; j.N[ji] = N; j.Kp[ji] = Kp;
        j.blk0[ji] = nblk; nblk += (N * Kp + 255) / 256; ++ji;
    };
    for (int b = 0; b < 2; ++b) addjob(win[b], w.winT + b * 512 * 128, F[b], 512, 128);
    for (int b = 0; b < 2; ++b)
        for (int l = 0; l < 3; ++l)
            addjob(ws3[b] + (size_t)l * 512 * 512,
                   w.wsT + ((size_t)b * 3 + l) * 512 * 512, 512, 512, 512);
    for (int b = 0; b < 2; ++b) addjob(wo[b], w.woutT + b * 128 * 512, 512, 128, 512);
    addjob(w_fc1, w.fc1T, 256, 1024, 256);
    addjob(w_fc2, w.fc2T, 1024, 512, 1024);
    j.blk0[12] = nblk;
    conv_all<<<nblk, 256, 0, stream>>>(j);

    // --- 2. CSR build, both branches (meta arrays always dual) ---
    init_deg<<<dim3(NN / 256, 1, 2), 256, 0, stream>>>(w.deg);
    count_edges2<<<(EM + EP + 255) / 256, 256, 0, stream>>>(mol_ei + EM, EM, pro_ei + EP, EP, w.deg);
    compute_dis<<<dim3(NN / 256, 1, 2), 256, 0, stream>>>(w.deg, w.dis);
    scan_offsets<<<dim3(1, 1, 2), 1024, 0, stream>>>(w.deg, w.offs, w.cur);
    scatter2<<<(EM + EP + 255) / 256, 256, 0, stream>>>(mol_ei, mol_ei + EM, EM,
                                                        pro_ei, pro_ei + EP, EP,
                                                        w.cur, w.srow0, w.srow1);

    // --- 3. branches ---
    auto branch_chain = [&](int zcount, int b0) {
        GArgs g{};
        // input GEMM: h = relu(xpad @ WinT + b); h0 = prev = h
        for (int z = 0; z < zcount; ++z) {
            int b = b0 + z;
            g.A[z] = w.xpad + z * XSTR;
            g.BT[z] = w.winT + b * 512 * 128;
            g.bias[z] = bin[b];
            g.C[z] = w.h0 + z * BSTR;
            g.C2[z] = w.prev + z * BSTR;
        }
        gemm_k<EPI_RELU2, 128><<<dim3(256, 4, zcount), 256, 0, stream>>>(g, HID);
        for (int l = 0; l < 3; ++l) {
            agg_kernel<<<dim3(NN, 1, zcount), 256, 0, stream>>>(
                w.prev, w.h0, w.dis, w.offs, w.srow0, w.srow1, w.sup, b0);
            GArgs gl{};
            for (int z = 0; z < zcount; ++z) {
                int b = b0 + z;
                gl.A[z] = w.sup + z * BSTR;
                gl.BT[z] = w.wsT + ((size_t)b * 3 + l) * 512 * 512;
                gl.S[z] = w.sup + z * BSTR;
                gl.P[z] = w.prev + z * BSTR;
            }
            gemm_k<EPI_GCN, 512><<<dim3(256, 4, zcount), 256, 0, stream>>>(gl, HID);
        }
        GArgs go{};
        for (int z = 0; z < zcount; ++z) {
            int b = b0 + z;
            go.A[z] = w.prev + z * BSTR;
            go.BT[z] = w.woutT + b * 128 * 512;
            go.bias[z] = bo[b];
            go.C[z] = w.xc;
            go.coff[z] = b * 128;
        }
        gemm_k<EPI_BIAS, 512><<<dim3(256, 1, zcount), 256, 0, stream>>>(go, 256);
    };

    if (comb) {
        pad_x2<<<dim3(NN * 128 / 256, 1, 2), 256, 0, stream>>>(mol_x, pro_x, F[0], F[1], w.xpad);
        branch_chain(2, 0);
    } else {
        for (int b = 0; b < 2; ++b) {
            pad_x2<<<dim3(NN * 128 / 256, 1, 1), 256, 0, stream>>>(
                b ? pro_x : mol_x, nullptr, F[b], 0, w.xpad);
            branch_chain(1, b);
        }
    }

    // --- 4. MLP head ---
    _Float16* x1 = w.h0;    // [NN,1024] aliases h0(+prev) block
    _Float16* x2 = w.sup;   // [NN,512]
    GArgs g1{};
    g1.A[0] = w.xc; g1.BT[0] = w.fc1T; g1.bias[0] = b_fc1; g1.C[0] = x1;
    gemm_k<EPI_RELU2, 256><<<dim3(256, 8, 1), 256, 0, stream>>>(g1, 1024);
    GArgs g2{};
    g2.A[0] = x1; g2.BT[0] = w.fc2T; g2.bias[0] = b_fc2; g2.C[0] = x2;
    gemm_k<EPI_RELU2, 1024><<<dim3(256, 4, 1), 256, 0, stream>>>(g2, 512);
    final_dot<<<NN / 4, 256, 0, stream>>>(x2, w_o, b_o, (float*)d_out);
    (void)in_sizes; (void)n_in; (void)out_size; (void)ws_size;
}

// Round 5
// 1095.988 us; speedup vs baseline: 1.2265x; 1.2265x over previous
//
#include <hip/hip_runtime.h>
#include <stdint.h>

#define NN 32768            // nodes
#define HID 512
#define EM 131072           // mol edges
#define EP 196608           // pro edges
#define AS1 __attribute__((address_space(1)))
#define AS3 __attribute__((address_space(3)))

typedef _Float16 h8 __attribute__((ext_vector_type(8)));
typedef _Float16 h2 __attribute__((ext_vector_type(2)));
typedef float f4 __attribute__((ext_vector_type(4)));

__device__ __forceinline__ void gload_lds16(const _Float16* g, _Float16* l) {
    __builtin_amdgcn_global_load_lds((AS1 void*)(g), (AS3 void*)(l), 16, 0, 0);
}

// ---------------- fused weight conversion: 12 transpose+cast jobs in one launch ----------------
struct ConvJobs {
    const float* src[12];
    _Float16* dst[12];
    int K[12], N[12], Kp[12];
    int blk0[13];   // cumulative block starts
};

__global__ void conv_all(ConvJobs j) {
    int blk = blockIdx.x, job = 0;
    while (blk >= j.blk0[job + 1]) ++job;
    int idx = (blk - j.blk0[job]) * 256 + threadIdx.x;
    int Kp = j.Kp[job], N = j.N[job], K = j.K[job];
    if (idx >= N * Kp) return;
    int n = idx / Kp, k = idx - n * Kp;
    j.dst[job][idx] = (k < K) ? (_Float16)j.src[job][(size_t)k * N + n] : (_Float16)0.f;
}

// pad+cast features fp32 [NN,F] -> fp16 [NN,128]; z selects branch (combined mode)
__global__ void pad_x2(const float* s0, const float* s1, int F0, int F1, _Float16* dstb) {
    int z = blockIdx.z;
    const float* src = z ? s1 : s0;
    int F = z ? F1 : F0;
    _Float16* dst = dstb + (size_t)z * NN * 128;
    int idx = blockIdx.x * 256 + threadIdx.x;
    int i = idx >> 7, jj = idx & 127;
    dst[idx] = (jj < F) ? (_Float16)src[(size_t)i * F + jj] : (_Float16)0.f;
}

// ---------------- CSR build (both branches always, meta arrays are [2][...]) ----------------
__global__ void init_deg(int* deg) {
    deg[(size_t)blockIdx.z * NN + blockIdx.x * 256 + threadIdx.x] = 1;  // self loop
}

__global__ void count_edges2(const int* c0, int E0, const int* c1, int E1, int* deg) {
    int i = blockIdx.x * 256 + threadIdx.x;
    if (i < E0) atomicAdd(&deg[c0[i]], 1);
    else { i -= E0; if (i < E1) atomicAdd(&deg[NN + c1[i]], 1); }
}

__global__ void compute_dis(const int* deg, float* dis) {
    int i = blockIdx.z * NN + blockIdx.x * 256 + threadIdx.x;
    dis[i] = rsqrtf((float)deg[i]);
}

// exclusive scan of (deg-1); one block per branch (blockIdx.z)
__global__ void scan_offsets(const int* degb, int* offsb, int* curb) {
    const int* deg = degb + blockIdx.z * NN;
    int* offs = offsb + blockIdx.z * (NN + 1);
    int* cur = curb + blockIdx.z * NN;
    __shared__ int part[1024];
    int t = threadIdx.x, base = t * 32;
    int loc[32], sum = 0;
    for (int j = 0; j < 32; ++j) { loc[j] = sum; sum += deg[base + j] - 1; }
    part[t] = sum;
    __syncthreads();
    for (int o = 1; o < 1024; o <<= 1) {
        int v = (t >= o) ? part[t - o] : 0;
        __syncthreads();
        part[t] += v;
        __syncthreads();
    }
    int pre = (t == 0) ? 0 : part[t - 1];
    for (int j = 0; j < 32; ++j) { int x = pre + loc[j]; offs[base + j] = x; cur[base + j] = x; }
    if (t == 1023) offs[NN] = part[1023];
}

__global__ void scatter2(const int* r0, const int* c0, int E0,
                         const int* r1, const int* c1, int E1,
                         int* cur, int* s0, int* s1) {
    int i = blockIdx.x * 256 + threadIdx.x;
    if (i < E0) { int p = atomicAdd(&cur[c0[i]], 1); s0[p] = r0[i]; }
    else { i -= E0; if (i < E1) { int p = atomicAdd(&cur[NN + c1[i]], 1); s1[p] = r1[i]; } }
}

// ---------------- aggregation: sup = 0.8*(D^-1/2 (A+I) D^-1/2 prev) + 0.2*h0 ----------------
__global__ void agg_kernel(const _Float16* prevb, const _Float16* h0b, const float* disb,
                           const int* offsb, const int* sr0, const int* sr1,
                           _Float16* supb, int mzadd) {
    const int z = blockIdx.z, mz = z + mzadd;
    const _Float16* prev = prevb + (size_t)z * NN * HID;
    const _Float16* h0 = h0b + (size_t)z * NN * HID;
    _Float16* sup = supb + (size_t)z * NN * HID;
    const float* dis = disb + mz * NN;
    const int* offs = offsb + mz * (NN + 1);
    const int* srow = mz ? sr1 : sr0;
    const int i = blockIdx.x, t = threadIdx.x;
    const size_t base = (size_t)i * HID + t * 2;
    const int e0 = offs[i], e1 = offs[i + 1];
    float a0 = 0.f, a1 = 0.f;
    int e = e0;
    for (; e + 1 < e1; e += 2) {  // unroll-2: two independent gathers in flight
        int ra = srow[e], rb = srow[e + 1];
        float sa = dis[ra], sb = dis[rb];
        h2 va = *(const h2*)&prev[(size_t)ra * HID + t * 2];
        h2 vb = *(const h2*)&prev[(size_t)rb * HID + t * 2];
        a0 += sa * (float)va[0] + sb * (float)vb[0];
        a1 += sa * (float)va[1] + sb * (float)vb[1];
    }
    if (e < e1) {
        int ra = srow[e];
        float sa = dis[ra];
        h2 va = *(const h2*)&prev[(size_t)ra * HID + t * 2];
        a0 += sa * (float)va[0];
        a1 += sa * (float)va[1];
    }
    float si = dis[i];
    h2 pv = *(const h2*)&prev[base];
    h2 hv = *(const h2*)&h0[base];
    float r0 = 0.8f * si * (a0 + si * (float)pv[0]) + 0.2f * (float)hv[0];
    float r1 = 0.8f * si * (a1 + si * (float)pv[1]) + 0.2f * (float)hv[1];
    h2 o; o[0] = (_Float16)r0; o[1] = (_Float16)r1;
    *(h2*)&sup[base] = o;
}

// ---------------- MFMA GEMM: 128 x (WN*128) tile, A via dbuf LDS, B per-frag from L2 --------
// 2*WN waves; wave tile 64x128 = 4x8 frags (128 AGPR). A staged once per row-slab (async
// global_load_lds, dbuf, 1 barrier/iter); B is the small reused operand -> global loads hit L2.
enum { EPI_RELU2 = 0, EPI_BIAS = 1, EPI_GCN = 2 };

struct GArgs {
    const _Float16* A[2];
    const _Float16* BT[2];
    const float* bias[2];
    _Float16* C[2];
    _Float16* C2[2];
    const _Float16* S[2];
    _Float16* P[2];
    int coff[2];
};

template <int EPI, int K, int WN>
__global__ __launch_bounds__(WN * 128, 2) void gemm_k(GArgs g, int ldc) {
    const int z = blockIdx.z;
    const _Float16* __restrict__ A = g.A[z];
    const _Float16* __restrict__ BT = g.BT[z];
    __shared__ _Float16 lA[2][8 * 128 * 8];     // dbuf A tile: [buf][k8][row][8]
    const int tid = threadIdx.x;
    const int wave = tid >> 6, lane = tid & 63;
    const int row0 = blockIdx.x * 128, col0 = blockIdx.y * (WN * 128);
    const int wm = wave & 1, wn = wave >> 1;    // wn in [0,WN)
    const int l15 = lane & 15, lq = lane >> 4;
    f4 acc[4][8] = {};
    constexpr int nk = K >> 6;
    constexpr int NI = 16 / (2 * WN);           // staging instrs per wave (16 total)

    auto stage = [&](int buf, int kt) {
        const int k0 = kt << 6;
        #pragma unroll
        for (int q = 0; q < NI; ++q) {
            const int c = wave * NI + q;
            const int k8 = c & 7, rh = c >> 3;
            gload_lds16(A + (size_t)(row0 + rh * 64 + lane) * K + k0 + k8 * 8,
                        &lA[buf][(k8 * 128 + rh * 64) * 8]);
        }
    };

    stage(0, 0);
    for (int kt = 0; kt < nk; ++kt) {
        const int b = kt & 1;
        __syncthreads();                         // drains vmcnt: buf b ready, buf b^1 free
        if (kt + 1 < nk) stage(b ^ 1, kt + 1);   // async prefetch, in flight across compute
        #pragma unroll
        for (int s = 0; s < 2; ++s) {
            const int kq = s * 4 + lq;
            h8 af[4], bf[8];
            #pragma unroll
            for (int rt = 0; rt < 4; ++rt)
                af[rt] = *(const h8*)&lA[b][(kq * 128 + wm * 64 + rt * 16 + l15) * 8];
            #pragma unroll
            for (int ct = 0; ct < 8; ++ct)
                bf[ct] = *(const h8*)(BT + (size_t)(col0 + wn * 128 + ct * 16 + l15) * K
                                      + kt * 64 + s * 32 + lq * 8);
            #pragma unroll
            for (int rt = 0; rt < 4; ++rt)
                #pragma unroll
                for (int ct = 0; ct < 8; ++ct)
                    acc[rt][ct] = __builtin_amdgcn_mfma_f32_16x16x32_f16(af[rt], bf[ct], acc[rt][ct], 0, 0, 0);
        }
    }
    // C/D frag mapping: col=lane&15, row=(lane>>4)*4+r (m89-verified)
    #pragma unroll
    for (int rt = 0; rt < 4; ++rt) {
        #pragma unroll
        for (int ct = 0; ct < 8; ++ct) {
            const int col = col0 + wn * 128 + ct * 16 + l15;
            #pragma unroll
            for (int r = 0; r < 4; ++r) {
                const int row = row0 + wm * 64 + rt * 16 + lq * 4 + r;
                float v = acc[rt][ct][r];
                if (EPI == EPI_RELU2) {
                    v = fmaxf(v + g.bias[z][col], 0.f);
                    g.C[z][(size_t)row * ldc + col] = (_Float16)v;
                    if (g.C2[z]) g.C2[z][(size_t)row * ldc + col] = (_Float16)v;
                } else if (EPI == EPI_BIAS) {
                    g.C[z][(size_t)row * ldc + g.coff[z] + col] = (_Float16)(v + g.bias[z][col]);
                } else {  // EPI_GCN: prev = relu(support + support@W) + prev
                    const size_t idx = (size_t)row * HID + col;
                    float nv = fmaxf((float)g.S[z][idx] + v, 0.f) + (float)g.P[z][idx];
                    g.P[z][idx] = (_Float16)nv;
                }
            }
        }
    }
}

// ---------------- final projection: out[i] = x2[i,:512] . w_o + b_o ----------------
__global__ void final_dot(const _Float16* __restrict__ x2, const float* __restrict__ w,
                          const float* __restrict__ b, float* __restrict__ out) {
    int wave = threadIdx.x >> 6, lane = threadIdx.x & 63;
    int row = blockIdx.x * 4 + wave;
    h8 v = *(const h8*)&x2[(size_t)row * 512 + lane * 8];
    float s = 0.f;
    #pragma unroll
    for (int j = 0; j < 8; ++j) s += (float)v[j] * w[lane * 8 + j];
    #pragma unroll
    for (int off = 32; off > 0; off >>= 1) s += __shfl_down(s, off);
    if (lane == 0) out[row] = s + b[0];
}

// ---------------- workspace plan ----------------
struct WS {
    int *deg, *offs, *cur, *srow0, *srow1;
    float* dis;
    _Float16 *winT, *wsT, *woutT, *fc1T, *fc2T;
    _Float16 *xpad, *h0, *prev, *sup, *xc;
    size_t total;
};

static WS plan(char* base, bool comb) {
    size_t off = 0;
    auto al = [&](size_t n) { off = (off + 255) & ~(size_t)255; size_t o = off; off += n; return base + o; };
    WS w;
    w.deg   = (int*)al(2 * NN * 4);
    w.dis   = (float*)al(2 * NN * 4);
    w.offs  = (int*)al(2 * (NN + 1) * 4);
    w.cur   = (int*)al(2 * NN * 4);
    w.srow0 = (int*)al((size_t)EM * 4);
    w.srow1 = (int*)al((size_t)EP * 4);
    w.winT  = (_Float16*)al(2 * 512 * 128 * 2);
    w.wsT   = (_Float16*)al((size_t)2 * 3 * 512 * 512 * 2);
    w.woutT = (_Float16*)al(2 * 128 * 512 * 2);
    w.fc1T  = (_Float16*)al(1024 * 256 * 2);
    w.fc2T  = (_Float16*)al((size_t)512 * 1024 * 2);
    size_t nb = comb ? 2 : 1;
    w.xpad = (_Float16*)al(nb * NN * 128 * 2);
    w.h0   = (_Float16*)al(nb * NN * HID * 2);   // h0 and prev contiguous: x1 [NN,1024] aliases h0(+prev)
    w.prev = (_Float16*)al(nb * NN * HID * 2);
    w.sup  = (_Float16*)al(nb * NN * HID * 2);
    w.xc   = (_Float16*)al((size_t)NN * 256 * 2);
    w.total = off;
    return w;
}

// ---------------- host orchestration ----------------
extern "C" void kernel_launch(void* const* d_in, const int* in_sizes, int n_in,
                              void* d_out, int out_size, void* d_ws, size_t ws_size,
                              hipStream_t stream) {
    const float* mol_x   = (const float*)d_in[0];
    const int*   mol_ei  = (const int*)d_in[1];
    const float* pro_x   = (const float*)d_in[2];
    const int*   pro_ei  = (const int*)d_in[3];
    const float* win[2]  = {(const float*)d_in[4], (const float*)d_in[9]};
    const float* bin[2]  = {(const float*)d_in[5], (const float*)d_in[10]};
    const float* ws3[2]  = {(const float*)d_in[6], (const float*)d_in[11]};
    const float* wo[2]   = {(const float*)d_in[7], (const float*)d_in[12]};
    const float* bo[2]   = {(const float*)d_in[8], (const float*)d_in[13]};
    const float* w_fc1   = (const float*)d_in[14];
    const float* b_fc1   = (const float*)d_in[15];
    const float* w_fc2   = (const float*)d_in[16];
    const float* b_fc2   = (const float*)d_in[17];
    const float* w_o     = (const float*)d_in[18];
    const float* b_o     = (const float*)d_in[19];
    const int F[2] = {78, 54};

    char* wsb = (char*)d_ws;
    WS w = plan(wsb, true);
    const bool comb = (w.total <= ws_size);
    if (!comb) w = plan(wsb, false);
    const size_t BSTR = comb ? (size_t)NN * HID : 0;       // branch stride for big fp16 arrays
    const size_t XSTR = comb ? (size_t)NN * 128 : 0;

    // --- 1. all weight conversions in one launch ---
    ConvJobs j;
    int nblk = 0, ji = 0;
    auto addjob = [&](const float* s, _Float16* d, int K, int N, int Kp) {
        j.src[ji] = s; j.dst[ji] = d; j.K[ji] = K; j.N[ji] = N; j.Kp[ji] = Kp;
        j.blk0[ji] = nblk; nblk += (N * Kp + 255) / 256; ++ji;
    };
    for (int b = 0; b < 2; ++b) addjob(win[b], w.winT + b * 512 * 128, F[b], 512, 128);
    for (int b = 0; b < 2; ++b)
        for (int l = 0; l < 3; ++l)
            addjob(ws3[b] + (size_t)l * 512 * 512,
                   w.wsT + ((size_t)b * 3 + l) * 512 * 512, 512, 512, 512);
    for (int b = 0; b < 2; ++b) addjob(wo[b], w.woutT + b * 128 * 512, 512, 128, 512);
    addjob(w_fc1, w.fc1T, 256, 1024, 256);
    addjob(w_fc2, w.fc2T, 1024, 512, 1024);
    j.blk0[12] = nblk;
    conv_all<<<nblk, 256, 0, stream>>>(j);

    // --- 2. CSR build, both branches (meta arrays always dual) ---
    init_deg<<<dim3(NN / 256, 1, 2), 256, 0, stream>>>(w.deg);
    count_edges2<<<(EM + EP + 255) / 256, 256, 0, stream>>>(mol_ei + EM, EM, pro_ei + EP, EP, w.deg);
    compute_dis<<<dim3(NN / 256, 1, 2), 256, 0, stream>>>(w.deg, w.dis);
    scan_offsets<<<dim3(1, 1, 2), 1024, 0, stream>>>(w.deg, w.offs, w.cur);
    scatter2<<<(EM + EP + 255) / 256, 256, 0, stream>>>(mol_ei, mol_ei + EM, EM,
                                                        pro_ei, pro_ei + EP, EP,
                                                        w.cur, w.srow0, w.srow1);

    // --- 3. branches ---
    auto branch_chain = [&](int zcount, int b0) {
        GArgs g{};
        // input GEMM: h = relu(xpad @ WinT + b); h0 = prev = h
        for (int z = 0; z < zcount; ++z) {
            int b = b0 + z;
            g.A[z] = w.xpad + z * XSTR;
            g.BT[z] = w.winT + b * 512 * 128;
            g.bias[z] = bin[b];
            g.C[z] = w.h0 + z * BSTR;
            g.C2[z] = w.prev + z * BSTR;
        }
        gemm_k<EPI_RELU2, 128, 4><<<dim3(256, 1, zcount), 512, 0, stream>>>(g, HID);
        for (int l = 0; l < 3; ++l) {
            agg_kernel<<<dim3(NN, 1, zcount), 256, 0, stream>>>(
                w.prev, w.h0, w.dis, w.offs, w.srow0, w.srow1, w.sup, b0);
            GArgs gl{};
            for (int z = 0; z < zcount; ++z) {
                int b = b0 + z;
                gl.A[z] = w.sup + z * BSTR;
                gl.BT[z] = w.wsT + ((size_t)b * 3 + l) * 512 * 512;
                gl.S[z] = w.sup + z * BSTR;
                gl.P[z] = w.prev + z * BSTR;
            }
            gemm_k<EPI_GCN, 512, 4><<<dim3(256, 1, zcount), 512, 0, stream>>>(gl, HID);
        }
        GArgs go{};
        for (int z = 0; z < zcount; ++z) {
            int b = b0 + z;
            go.A[z] = w.prev + z * BSTR;
            go.BT[z] = w.woutT + b * 128 * 512;
            go.bias[z] = bo[b];
            go.C[z] = w.xc;
            go.coff[z] = b * 128;
        }
        gemm_k<EPI_BIAS, 512, 1><<<dim3(256, 1, zcount), 128, 0, stream>>>(go, 256);
    };

    if (comb) {
        pad_x2<<<dim3(NN * 128 / 256, 1, 2), 256, 0, stream>>>(mol_x, pro_x, F[0], F[1], w.xpad);
        branch_chain(2, 0);
    } else {
        for (int b = 0; b < 2; ++b) {
            pad_x2<<<dim3(NN * 128 / 256, 1, 1), 256, 0, stream>>>(
                b ? pro_x : mol_x, nullptr, F[b], 0, w.xpad);
            branch_chain(1, b);
        }
    }

    // --- 4. MLP head ---
    _Float16* x1 = w.h0;    // [NN,1024] aliases h0(+prev) block
    _Float16* x2 = w.sup;   // [NN,512]
    GArgs g1{};
    g1.A[0] = w.xc; g1.BT[0] = w.fc1T; g1.bias[0] = b_fc1; g1.C[0] = x1;
    gemm_k<EPI_RELU2, 256, 4><<<dim3(256, 2, 1), 512, 0, stream>>>(g1, 1024);
    GArgs g2{};
    g2.A[0] = x1; g2.BT[0] = w.fc2T; g2.bias[0] = b_fc2; g2.C[0] = x2;
    gemm_k<EPI_RELU2, 1024, 4><<<dim3(256, 1, 1), 512, 0, stream>>>(g2, 512);
    final_dot<<<NN / 4, 256, 0, stream>>>(x2, w_o, b_o, (float*)d_out);
    (void)in_sizes; (void)n_in; (void)out_size; (void)ws_size;
}

// Round 6
// 1044.613 us; speedup vs baseline: 1.2868x; 1.0492x over previous
//
#include <hip/hip_runtime.h>
#include <stdint.h>

#define NN 32768            // nodes
#define HID 512
#define EM 131072           // mol edges
#define EP 196608           // pro edges
#define AS1 __attribute__((address_space(1)))
#define AS3 __attribute__((address_space(3)))

typedef _Float16 h8 __attribute__((ext_vector_type(8)));
typedef _Float16 h2 __attribute__((ext_vector_type(2)));
typedef float f4 __attribute__((ext_vector_type(4)));
typedef float f8 __attribute__((ext_vector_type(8)));

__device__ __forceinline__ void gload_lds16(const _Float16* g, _Float16* l) {
    __builtin_amdgcn_global_load_lds((AS1 void*)(g), (AS3 void*)(l), 16, 0, 0);
}

// ---------------- fused weight conversion: 12 transpose+cast jobs in one launch ----------------
struct ConvJobs {
    const float* src[12];
    _Float16* dst[12];
    int K[12], N[12], Kp[12];
    int blk0[13];   // cumulative block starts
};

__global__ void conv_all(ConvJobs j) {
    int blk = blockIdx.x, job = 0;
    while (blk >= j.blk0[job + 1]) ++job;
    int idx = (blk - j.blk0[job]) * 256 + threadIdx.x;
    int Kp = j.Kp[job], N = j.N[job], K = j.K[job];
    if (idx >= N * Kp) return;
    int n = idx / Kp, k = idx - n * Kp;
    j.dst[job][idx] = (k < K) ? (_Float16)j.src[job][(size_t)k * N + n] : (_Float16)0.f;
}

// pad+cast features fp32 [NN,F] -> fp16 [NN,128]; z selects branch (combined mode)
__global__ void pad_x2(const float* s0, const float* s1, int F0, int F1, _Float16* dstb) {
    int z = blockIdx.z;
    const float* src = z ? s1 : s0;
    int F = z ? F1 : F0;
    _Float16* dst = dstb + (size_t)z * NN * 128;
    int idx = blockIdx.x * 256 + threadIdx.x;
    int i = idx >> 7, jj = idx & 127;
    dst[idx] = (jj < F) ? (_Float16)src[(size_t)i * F + jj] : (_Float16)0.f;
}

// ---------------- CSR build (both branches always, meta arrays are [2][...]) ----------------
__global__ void init_deg(int* deg) {
    deg[(size_t)blockIdx.z * NN + blockIdx.x * 256 + threadIdx.x] = 1;  // self loop
}

__global__ void count_edges2(const int* c0, int E0, const int* c1, int E1, int* deg) {
    int i = blockIdx.x * 256 + threadIdx.x;
    if (i < E0) atomicAdd(&deg[c0[i]], 1);
    else { i -= E0; if (i < E1) atomicAdd(&deg[NN + c1[i]], 1); }
}

__global__ void compute_dis(const int* deg, float* dis) {
    int i = blockIdx.z * NN + blockIdx.x * 256 + threadIdx.x;
    dis[i] = rsqrtf((float)deg[i]);
}

// exclusive scan of (deg-1); one block per branch (blockIdx.z)
__global__ void scan_offsets(const int* degb, int* offsb, int* curb) {
    const int* deg = degb + blockIdx.z * NN;
    int* offs = offsb + blockIdx.z * (NN + 1);
    int* cur = curb + blockIdx.z * NN;
    __shared__ int part[1024];
    int t = threadIdx.x, base = t * 32;
    int loc[32], sum = 0;
    for (int j = 0; j < 32; ++j) { loc[j] = sum; sum += deg[base + j] - 1; }
    part[t] = sum;
    __syncthreads();
    for (int o = 1; o < 1024; o <<= 1) {
        int v = (t >= o) ? part[t - o] : 0;
        __syncthreads();
        part[t] += v;
        __syncthreads();
    }
    int pre = (t == 0) ? 0 : part[t - 1];
    for (int j = 0; j < 32; ++j) { int x = pre + loc[j]; offs[base + j] = x; cur[base + j] = x; }
    if (t == 1023) offs[NN] = part[1023];
}

__global__ void scatter2(const int* r0, const int* c0, int E0,
                         const int* r1, const int* c1, int E1,
                         int* cur, int* s0, int* s1) {
    int i = blockIdx.x * 256 + threadIdx.x;
    if (i < E0) { int p = atomicAdd(&cur[c0[i]], 1); s0[p] = r0[i]; }
    else { i -= E0; if (i < E1) { int p = atomicAdd(&cur[NN + c1[i]], 1); s1[p] = r1[i]; } }
}

// ---------------- fused layer: sup(gather)->LDS, then sup@W GEMM + GCNII epilogue -----------
// Block = 128 rows x full N=512. Phase 1: gather sup rows into LDS (prev is L3-resident).
// One barrier. Phase 2: barrier-free GEMM -- A frags via ds_read_b128 (row stride 536 halfs:
// 16B-aligned, 2-way-max bank aliasing = free), B frags from global (512KB weight, L2-hot,
// loads pipeline freely under vmcnt since no barrier follows). Epilogue:
//   pout = relu(sup + sup@W) + pin   (ping-pong pin/pout: no cross-block race).
#define ROWP 536

__global__ __launch_bounds__(512) void layer_fused(
    const _Float16* pinb, const _Float16* h0b, _Float16* poutb,
    const float* disb, const int* offsb, const int* sr0, const int* sr1,
    const _Float16* wTb, size_t bstr, int mzadd) {
    extern __shared__ _Float16 sup[];   // [128][ROWP]
    const int z = blockIdx.z, mz = z + mzadd;
    const _Float16* __restrict__ pin = pinb + (size_t)z * bstr;
    const _Float16* __restrict__ h0 = h0b + (size_t)z * bstr;
    _Float16* __restrict__ pout = poutb + (size_t)z * bstr;
    const _Float16* __restrict__ BT = wTb + (size_t)z * (3 * 512 * 512);
    const float* __restrict__ dis = disb + mz * NN;
    const int* __restrict__ offs = offsb + mz * (NN + 1);
    const int* __restrict__ srow = mz ? sr1 : sr0;
    const int tid = threadIdx.x, wave = tid >> 6, lane = tid & 63;
    const int row0 = blockIdx.x * 128;

    // ---- phase 1: gather 16 rows per wave; 4-wide independent-load batches ----
    for (int i = 0; i < 16; ++i) {
        const int rl = wave * 16 + i, row = row0 + rl;
        const int e0 = offs[row], e1 = offs[row + 1];
        f8 a = {};
        for (int e = e0; e < e1; e += 4) {
            const int j1 = (e + 1 < e1) ? e + 1 : e;
            const int j2 = (e + 2 < e1) ? e + 2 : e;
            const int j3 = (e + 3 < e1) ? e + 3 : e;
            const float m1 = (e + 1 < e1) ? 1.f : 0.f;
            const float m2 = (e + 2 < e1) ? 1.f : 0.f;
            const float m3 = (e + 3 < e1) ? 1.f : 0.f;
            const int r0 = srow[e], r1 = srow[j1], r2 = srow[j2], r3 = srow[j3];
            const float s0 = dis[r0], s1 = dis[r1] * m1, s2 = dis[r2] * m2, s3 = dis[r3] * m3;
            h8 v0 = *(const h8*)&pin[(size_t)r0 * 512 + lane * 8];
            h8 v1 = *(const h8*)&pin[(size_t)r1 * 512 + lane * 8];
            h8 v2 = *(const h8*)&pin[(size_t)r2 * 512 + lane * 8];
            h8 v3 = *(const h8*)&pin[(size_t)r3 * 512 + lane * 8];
            a += s0 * __builtin_convertvector(v0, f8) + s1 * __builtin_convertvector(v1, f8)
               + s2 * __builtin_convertvector(v2, f8) + s3 * __builtin_convertvector(v3, f8);
        }
        const float si = dis[row];
        h8 pv = *(const h8*)&pin[(size_t)row * 512 + lane * 8];
        h8 hv = *(const h8*)&h0[(size_t)row * 512 + lane * 8];
        f8 r = 0.8f * si * (a + si * __builtin_convertvector(pv, f8))
             + 0.2f * __builtin_convertvector(hv, f8);
        *(h8*)&sup[rl * ROWP + lane * 8] = __builtin_convertvector(r, h8);
    }
    __syncthreads();

    // ---- phase 2: GEMM, no barriers ----
    const int wm = wave & 1, wn = wave >> 1;          // 2 x 4 wave grid, wave tile 64x128
    const int l15 = lane & 15, lq = lane >> 4;
    f4 acc[4][8] = {};
    #pragma unroll
    for (int kt = 0; kt < 8; ++kt) {
        #pragma unroll
        for (int s = 0; s < 2; ++s) {
            const int koff = kt * 64 + s * 32 + lq * 8;
            h8 af[4], bf[8];
            #pragma unroll
            for (int rt = 0; rt < 4; ++rt)
                af[rt] = *(const h8*)&sup[(wm * 64 + rt * 16 + l15) * ROWP + koff];
            #pragma unroll
            for (int ct = 0; ct < 8; ++ct)
                bf[ct] = *(const h8*)(BT + (size_t)(wn * 128 + ct * 16 + l15) * 512 + koff);
            #pragma unroll
            for (int rt = 0; rt < 4; ++rt)
                #pragma unroll
                for (int ct = 0; ct < 8; ++ct)
                    acc[rt][ct] = __builtin_amdgcn_mfma_f32_16x16x32_f16(af[rt], bf[ct], acc[rt][ct], 0, 0, 0);
        }
    }
    // ---- epilogue: pout = relu(sup + sup@W) + pin ----
    #pragma unroll
    for (int rt = 0; rt < 4; ++rt) {
        #pragma unroll
        for (int ct = 0; ct < 8; ++ct) {
            const int col = wn * 128 + ct * 16 + l15;
            #pragma unroll
            for (int r = 0; r < 4; ++r) {
                const int rl = wm * 64 + rt * 16 + lq * 4 + r;
                const size_t gi = (size_t)(row0 + rl) * 512 + col;
                float nv = fmaxf((float)sup[rl * ROWP + col] + acc[rt][ct][r], 0.f) + (float)pin[gi];
                pout[gi] = (_Float16)nv;
            }
        }
    }
}

// ---------------- MFMA GEMM (R2 structure: 128x128 tile, BK=64, 2 barriers/iter) ------------
enum { EPI_RELU2 = 0, EPI_BIAS = 1 };

struct GArgs {
    const _Float16* A[2];
    const _Float16* BT[2];
    const float* bias[2];
    _Float16* C[2];
    _Float16* C2[2];
    int coff[2];
};

template <int EPI>
__global__ __launch_bounds__(256) void gemm_k(GArgs g, int K, int ldc) {
    const int z = blockIdx.z;
    const _Float16* __restrict__ A = g.A[z];
    const _Float16* __restrict__ BT = g.BT[z];
    __shared__ _Float16 lA[8 * 128 * 8];
    __shared__ _Float16 lB[8 * 128 * 8];
    const int tid = threadIdx.x;
    const int wave = tid >> 6, lane = tid & 63;
    const int row0 = blockIdx.x * 128, col0 = blockIdx.y * 128;
    const int wm = wave & 1, wn = wave >> 1;
    f4 acc[4][4] = {};
    const int nk = K >> 6;
    for (int kt = 0; kt < nk; ++kt) {
        const int k0 = kt << 6;
        __syncthreads();
        #pragma unroll
        for (int q = 0; q < 4; ++q) {
            const int c = wave * 4 + q;
            const int k8 = c & 7, rh = c >> 3;
            gload_lds16(A + (size_t)(row0 + rh * 64 + lane) * K + k0 + k8 * 8,
                        &lA[(k8 * 128 + rh * 64) * 8]);
            gload_lds16(BT + (size_t)(col0 + rh * 64 + lane) * K + k0 + k8 * 8,
                        &lB[(k8 * 128 + rh * 64) * 8]);
        }
        __syncthreads();
        #pragma unroll
        for (int s = 0; s < 2; ++s) {
            h8 af[4], bf[4];
            const int kq = s * 4 + (lane >> 4);
            #pragma unroll
            for (int t = 0; t < 4; ++t) {
                af[t] = *(const h8*)&lA[(kq * 128 + wm * 64 + t * 16 + (lane & 15)) * 8];
                bf[t] = *(const h8*)&lB[(kq * 128 + wn * 64 + t * 16 + (lane & 15)) * 8];
            }
            #pragma unroll
            for (int rt = 0; rt < 4; ++rt)
                #pragma unroll
                for (int ct = 0; ct < 4; ++ct)
                    acc[rt][ct] = __builtin_amdgcn_mfma_f32_16x16x32_f16(af[rt], bf[ct], acc[rt][ct], 0, 0, 0);
        }
    }
    #pragma unroll
    for (int rt = 0; rt < 4; ++rt) {
        #pragma unroll
        for (int ct = 0; ct < 4; ++ct) {
            const int col = col0 + wn * 64 + ct * 16 + (lane & 15);
            #pragma unroll
            for (int r = 0; r < 4; ++r) {
                const int row = row0 + wm * 64 + rt * 16 + (lane >> 4) * 4 + r;
                float v = acc[rt][ct][r];
                if (EPI == EPI_RELU2) {
                    v = fmaxf(v + g.bias[z][col], 0.f);
                    g.C[z][(size_t)row * ldc + col] = (_Float16)v;
                    if (g.C2[z]) g.C2[z][(size_t)row * ldc + col] = (_Float16)v;
                } else {
                    g.C[z][(size_t)row * ldc + g.coff[z] + col] = (_Float16)(v + g.bias[z][col]);
                }
            }
        }
    }
}

// ---------------- final projection: out[i] = x2[i,:512] . w_o + b_o ----------------
__global__ void final_dot(const _Float16* __restrict__ x2, const float* __restrict__ w,
                          const float* __restrict__ b, float* __restrict__ out) {
    int wave = threadIdx.x >> 6, lane = threadIdx.x & 63;
    int row = blockIdx.x * 4 + wave;
    h8 v = *(const h8*)&x2[(size_t)row * 512 + lane * 8];
    float s = 0.f;
    #pragma unroll
    for (int j = 0; j < 8; ++j) s += (float)v[j] * w[lane * 8 + j];
    #pragma unroll
    for (int off = 32; off > 0; off >>= 1) s += __shfl_down(s, off);
    if (lane == 0) out[row] = s + b[0];
}

// ---------------- workspace plan ----------------
struct WS {
    int *deg, *offs, *cur, *srow0, *srow1;
    float* dis;
    _Float16 *winT, *wsT, *woutT, *fc1T, *fc2T;
    _Float16 *xpad, *h0, *prev0, *prev1, *xc;
    size_t total;
};

static WS plan(char* base, bool comb) {
    size_t off = 0;
    auto al = [&](size_t n) { off = (off + 255) & ~(size_t)255; size_t o = off; off += n; return base + o; };
    WS w;
    w.deg   = (int*)al(2 * NN * 4);
    w.dis   = (float*)al(2 * NN * 4);
    w.offs  = (int*)al(2 * (NN + 1) * 4);
    w.cur   = (int*)al(2 * NN * 4);
    w.srow0 = (int*)al((size_t)EM * 4);
    w.srow1 = (int*)al((size_t)EP * 4);
    w.winT  = (_Float16*)al(2 * 512 * 128 * 2);
    w.wsT   = (_Float16*)al((size_t)2 * 3 * 512 * 512 * 2);
    w.woutT = (_Float16*)al(2 * 128 * 512 * 2);
    w.fc1T  = (_Float16*)al(1024 * 256 * 2);
    w.fc2T  = (_Float16*)al((size_t)512 * 1024 * 2);
    size_t nb = comb ? 2 : 1;
    w.xpad  = (_Float16*)al(nb * NN * 128 * 2);
    w.h0    = (_Float16*)al(nb * NN * HID * 2);   // h0+prev0 contiguous: x1 [NN,1024] aliases them
    w.prev0 = (_Float16*)al(nb * NN * HID * 2);
    w.prev1 = (_Float16*)al(nb * NN * HID * 2);
    w.xc    = (_Float16*)al((size_t)NN * 256 * 2);
    w.total = off;
    return w;
}

// ---------------- host orchestration ----------------
extern "C" void kernel_launch(void* const* d_in, const int* in_sizes, int n_in,
                              void* d_out, int out_size, void* d_ws, size_t ws_size,
                              hipStream_t stream) {
    const float* mol_x   = (const float*)d_in[0];
    const int*   mol_ei  = (const int*)d_in[1];
    const float* pro_x   = (const float*)d_in[2];
    const int*   pro_ei  = (const int*)d_in[3];
    const float* win[2]  = {(const float*)d_in[4], (const float*)d_in[9]};
    const float* bin[2]  = {(const float*)d_in[5], (const float*)d_in[10]};
    const float* ws3[2]  = {(const float*)d_in[6], (const float*)d_in[11]};
    const float* wo[2]   = {(const float*)d_in[7], (const float*)d_in[12]};
    const float* bo[2]   = {(const float*)d_in[8], (const float*)d_in[13]};
    const float* w_fc1   = (const float*)d_in[14];
    const float* b_fc1   = (const float*)d_in[15];
    const float* w_fc2   = (const float*)d_in[16];
    const float* b_fc2   = (const float*)d_in[17];
    const float* w_o     = (const float*)d_in[18];
    const float* b_o     = (const float*)d_in[19];
    const int F[2] = {78, 54};

    char* wsb = (char*)d_ws;
    WS w = plan(wsb, true);
    const bool comb = (w.total <= ws_size);
    if (!comb) w = plan(wsb, false);
    const size_t BSTR = comb ? (size_t)NN * HID : 0;       // branch stride for big fp16 arrays
    const size_t XSTR = comb ? (size_t)NN * 128 : 0;
    const int LDSB = 128 * ROWP * 2;                        // 137216 B dynamic LDS

    hipFuncSetAttribute((const void*)layer_fused,
                        hipFuncAttributeMaxDynamicSharedMemorySize, LDSB);

    // --- 1. all weight conversions in one launch ---
    ConvJobs j;
    int nblk = 0, ji = 0;
    auto addjob = [&](const float* s, _Float16* d, int K, int N, int Kp) {
        j.src[ji] = s; j.dst[ji] = d; j.K[ji] = K; j.N[ji] = N; j.Kp[ji] = Kp;
        j.blk0[ji] = nblk; nblk += (N * Kp + 255) / 256; ++ji;
    };
    for (int b = 0; b < 2; ++b) addjob(win[b], w.winT + b * 512 * 128, F[b], 512, 128);
    for (int b = 0; b < 2; ++b)
        for (int l = 0; l < 3; ++l)
            addjob(ws3[b] + (size_t)l * 512 * 512,
                   w.wsT + ((size_t)b * 3 + l) * 512 * 512, 512, 512, 512);
    for (int b = 0; b < 2; ++b) addjob(wo[b], w.woutT + b * 128 * 512, 512, 128, 512);
    addjob(w_fc1, w.fc1T, 256, 1024, 256);
    addjob(w_fc2, w.fc2T, 1024, 512, 1024);
    j.blk0[12] = nblk;
    conv_all<<<nblk, 256, 0, stream>>>(j);

    // --- 2. CSR build, both branches (meta arrays always dual) ---
    init_deg<<<dim3(NN / 256, 1, 2), 256, 0, stream>>>(w.deg);
    count_edges2<<<(EM + EP + 255) / 256, 256, 0, stream>>>(mol_ei + EM, EM, pro_ei + EP, EP, w.deg);
    compute_dis<<<dim3(NN / 256, 1, 2), 256, 0, stream>>>(w.deg, w.dis);
    scan_offsets<<<dim3(1, 1, 2), 1024, 0, stream>>>(w.deg, w.offs, w.cur);
    scatter2<<<(EM + EP + 255) / 256, 256, 0, stream>>>(mol_ei, mol_ei + EM, EM,
                                                        pro_ei, pro_ei + EP, EP,
                                                        w.cur, w.srow0, w.srow1);

    // --- 3. branches ---
    auto branch_chain = [&](int zcount, int b0) {
        GArgs g{};
        for (int z = 0; z < zcount; ++z) {
            int b = b0 + z;
            g.A[z] = w.xpad + z * XSTR;
            g.BT[z] = w.winT + b * 512 * 128;
            g.bias[z] = bin[b];
            g.C[z] = w.h0 + z * BSTR;
            g.C2[z] = w.prev0 + z * BSTR;
        }
        gemm_k<EPI_RELU2><<<dim3(256, 4, zcount), 256, 0, stream>>>(g, 128, HID);
        _Float16* pp[2] = {w.prev0, w.prev1};
        for (int l = 0; l < 3; ++l) {
            layer_fused<<<dim3(256, 1, zcount), 512, LDSB, stream>>>(
                pp[l & 1], w.h0, pp[(l & 1) ^ 1], w.dis, w.offs, w.srow0, w.srow1,
                w.wsT + ((size_t)b0 * 3 + l) * 512 * 512, BSTR, b0);
        }
        GArgs go{};
        for (int z = 0; z < zcount; ++z) {
            int b = b0 + z;
            go.A[z] = w.prev1 + z * BSTR;    // after 3 layers result is in prev1
            go.BT[z] = w.woutT + b * 128 * 512;
            go.bias[z] = bo[b];
            go.C[z] = w.xc;
            go.coff[z] = b * 128;
        }
        gemm_k<EPI_BIAS><<<dim3(256, 1, zcount), 256, 0, stream>>>(go, 512, 256);
    };

    if (comb) {
        pad_x2<<<dim3(NN * 128 / 256, 1, 2), 256, 0, stream>>>(mol_x, pro_x, F[0], F[1], w.xpad);
        branch_chain(2, 0);
    } else {
        for (int b = 0; b < 2; ++b) {
            pad_x2<<<dim3(NN * 128 / 256, 1, 1), 256, 0, stream>>>(
                b ? pro_x : mol_x, nullptr, F[b], 0, w.xpad);
            branch_chain(1, b);
        }
    }

    // --- 4. MLP head ---
    _Float16* x1 = w.h0;     // [NN,1024] aliases h0(+prev0) block (free after branches)
    _Float16* x2 = w.prev1;  // [NN,512]  (free after out-GEMMs)
    GArgs g1{};
    g1.A[0] = w.xc; g1.BT[0] = w.fc1T; g1.bias[0] = b_fc1; g1.C[0] = x1;
    gemm_k<EPI_RELU2><<<dim3(256, 8, 1), 256, 0, stream>>>(g1, 256, 1024);
    GArgs g2{};
    g2.A[0] = x1; g2.BT[0] = w.fc2T; g2.bias[0] = b_fc2; g2.C[0] = x2;
    gemm_k<EPI_RELU2><<<dim3(256, 4, 1), 256, 0, stream>>>(g2, 1024, 512);
    final_dot<<<NN / 4, 256, 0, stream>>>(x2, w_o, b_o, (float*)d_out);
    (void)in_sizes; (void)n_in; (void)out_size; (void)ws_size;
}